// Round 12
// baseline (140.483 us; speedup 1.0000x reference)
//
#include <hip/hip_runtime.h>

#define OUT_DIM 300

typedef _Float16 half4_t __attribute__((ext_vector_type(4)));
typedef _Float16 half8_t __attribute__((ext_vector_type(8)));

// ---------------------------------------------------------------------------
// Fused setup. Blocks [0, scat_blocks): row_ptr boundary scatter (rows sorted).
// Remainder: XCD-matched repack fp32 -> f16, 4 slices {80,80,80,60} cols,
// stride 160 B. Repack block slice = blockIdx%4, so with round-robin
// block->XCD the writer XCD is in {s, s+4} — the same XCDs that gather slice
// s in spmm -> repacked lines sit dirty in the reader's L2.
__global__ __launch_bounds__(256) void setup4x_kernel(
    const int* __restrict__ rows, int* __restrict__ row_ptr,
    const float* __restrict__ w, unsigned char* __restrict__ wf,
    int nnz, int batch, int in_dim, int scat_blocks)
{
    if ((int)blockIdx.x < scat_blocks) {
        int i = blockIdx.x * 256 + threadIdx.x;
        if (i >= nnz) return;
        int r = rows[i];
        int prev = (i == 0) ? -1 : rows[i - 1];
        for (int q = prev + 1; q <= r; ++q) row_ptr[q] = i;
        if (i == nnz - 1)
            for (int q = r + 1; q <= batch; ++q) row_ptr[q] = nnz;
        return;
    }
    const int s  = (int)blockIdx.x & 3;                  // slice (XCD-matched)
    const int q  = ((int)blockIdx.x - scat_blocks) >> 2; // portion within slice
    const int ng = (s == 3) ? 15 : 20;                   // float4 groups/row
    int i = q * 256 + (int)threadIdx.x;
    if (i >= in_dim * ng) return;
    int r = i / ng;
    int g = i - r * ng;
    const float4 f = *(const float4*)(w + (size_t)r * OUT_DIM + 80 * s + 4 * g);
    half4_t h;
    h[0] = (_Float16)f.x; h[1] = (_Float16)f.y;
    h[2] = (_Float16)f.z; h[3] = (_Float16)f.w;
    *(half4_t*)(wf + ((size_t)s * in_dim + r) * 160 + g * 8) = h;
}

// ---------------------------------------------------------------------------
// 4-slice SpMM, 4 rows per wave. Block b: slice b&3, wave w handles rows
// [((b>>2)*4+w)*4, +4). (cols,vals) staged in 64-nnz chunks spanning row
// boundaries; rounds of 6 nnz (6 groups x 10 lanes, half8 loads); row-end
// clamp redirects out-of-segment slots to zero-slot 96.
__global__ __launch_bounds__(256) void spmm4r(
    const int* __restrict__ row_ptr,
    const int* __restrict__ cols,
    const float* __restrict__ vals,
    const unsigned char* __restrict__ wf,
    const float* __restrict__ bias,
    float* __restrict__ out,
    int batch, int in_dim)
{
    __shared__ uint2 sh[4][104];          // slots 0..63 staged, 96 = zero slot

    const int slice = blockIdx.x & 3;
    const int wave  = threadIdx.x >> 6;
    const int lane  = threadIdx.x & 63;
    const int r0    = ((blockIdx.x >> 2) * 4 + wave) * 4;
    if (r0 >= batch) return;

    const int grp = lane / 10;            // 0..6 (6 = prefetch lanes 60..63)
    const int ch  = lane - grp * 10;      // 0..9
    const int choff = ch * 16;

    const unsigned char* wslice = wf + (size_t)slice * in_dim * 160;
    uint2* shw = sh[wave];                // wave-private: no __syncthreads
    if (lane == 0) shw[96] = make_uint2(0u, 0u);

    // Wave-uniform row pointers for 4 rows.
    int rp[5];
#pragma unroll
    for (int i = 0; i < 5; ++i) {
        int rr = r0 + i; if (rr > batch) rr = batch;
        rp[i] = row_ptr[rr];
    }

    int cb = rp[0];                       // staged chunk base
    {
        int cnt = rp[4] - cb; if (cnt > 64) cnt = 64;
        uint2 ov = make_uint2(0u, 0u);
        if (lane < cnt) {
            ov.x = (unsigned)(cols[cb + lane] * 160);
            ov.y = __float_as_uint(vals[cb + lane]);
        }
        shw[lane] = ov;
    }

#pragma unroll
    for (int i = 0; i < 4; ++i) {
        const int rowi = r0 + i;
        if (rowi >= batch) break;
        const int eR = rp[i + 1];
        int cur = rp[i];

        float a0 = 0.f, a1 = 0.f, a2 = 0.f, a3 = 0.f;
        float a4 = 0.f, a5 = 0.f, a6 = 0.f, a7 = 0.f;

        for (;;) {
            const int s0 = cur - cb;              // segment start in chunk
            int e = eR - cb; if (e > 64) e = 64;  // segment end in chunk
            const int nr = e - s0;
            if (nr > 0) {
                const int rr  = (nr + 5) / 6;
                const int rrp = (rr + 3) & ~3;
                for (int z = 0; z < rrp; z += 4) {
#pragma unroll
                    for (int u = 0; u < 4; ++u) {
                        int slot = s0 + 6 * (z + u) + grp;
                        slot = (slot < e) ? slot : 96;     // clamp to zero slot
                        uint2 qq = shw[slot];
                        float v = __uint_as_float(qq.y);
                        half8_t wv = *(const half8_t*)(wslice + qq.x + choff);
                        a0 += v * (float)wv[0];            // v_fma_mix_f32
                        a1 += v * (float)wv[1];
                        a2 += v * (float)wv[2];
                        a3 += v * (float)wv[3];
                        a4 += v * (float)wv[4];
                        a5 += v * (float)wv[5];
                        a6 += v * (float)wv[6];
                        a7 += v * (float)wv[7];
                    }
                }
            }
            if (eR > cb + 64) {                   // row continues: restage
                cb += 64;
                int cnt = rp[4] - cb; if (cnt > 64) cnt = 64;
                uint2 ov = make_uint2(0u, 0u);
                if (lane < cnt) {
                    ov.x = (unsigned)(cols[cb + lane] * 160);
                    ov.y = __float_as_uint(vals[cb + lane]);
                }
                shw[lane] = ov;
                cur = cb;
            } else break;
        }

        // Fold 6 groups: g0..2 += g3..5 (shfl 30), then g0 += g1 + g2.
        a0 += __shfl_down(a0, 30); a1 += __shfl_down(a1, 30);
        a2 += __shfl_down(a2, 30); a3 += __shfl_down(a3, 30);
        a4 += __shfl_down(a4, 30); a5 += __shfl_down(a5, 30);
        a6 += __shfl_down(a6, 30); a7 += __shfl_down(a7, 30);

        float f0 = a0 + __shfl_down(a0, 10) + __shfl_down(a0, 20);
        float f1 = a1 + __shfl_down(a1, 10) + __shfl_down(a1, 20);
        float f2 = a2 + __shfl_down(a2, 10) + __shfl_down(a2, 20);
        float f3 = a3 + __shfl_down(a3, 10) + __shfl_down(a3, 20);
        float f4 = a4 + __shfl_down(a4, 10) + __shfl_down(a4, 20);
        float f5 = a5 + __shfl_down(a5, 10) + __shfl_down(a5, 20);
        float f6 = a6 + __shfl_down(a6, 10) + __shfl_down(a6, 20);
        float f7 = a7 + __shfl_down(a7, 10) + __shfl_down(a7, 20);

        const int nlan = (slice == 3) ? 8 : 10;
        if (lane < nlan) {
            const int col = slice * 80 + lane * 8;       // 16B-aligned
            float* orow = out + (size_t)rowi * OUT_DIM + col;
            const float4 b0 = *(const float4*)(bias + col);
            float4 s0v;
            s0v.x = fmaxf(f0 + b0.x, 0.f);
            s0v.y = fmaxf(f1 + b0.y, 0.f);
            s0v.z = fmaxf(f2 + b0.z, 0.f);
            s0v.w = fmaxf(f3 + b0.w, 0.f);
            *(float4*)orow = s0v;
            if (slice < 3 || lane < 7) {                 // lane7@s3: 296..299
                const float4 b1 = *(const float4*)(bias + col + 4);
                float4 s1v;
                s1v.x = fmaxf(f4 + b1.x, 0.f);
                s1v.y = fmaxf(f5 + b1.y, 0.f);
                s1v.z = fmaxf(f6 + b1.z, 0.f);
                s1v.w = fmaxf(f7 + b1.w, 0.f);
                *(float4*)(orow + 4) = s1v;
            }
        }
    }
}

// ---------------------------------------------------------------------------
// Last-resort fp32 path (tiny ws).
__global__ __launch_bounds__(256) void row_ptr_scatter(
    const int* __restrict__ rows, int* __restrict__ row_ptr, int nnz, int batch)
{
    int i = blockIdx.x * 256 + threadIdx.x;
    if (i >= nnz) return;
    int r = rows[i];
    int prev = (i == 0) ? -1 : rows[i - 1];
    for (int q = prev + 1; q <= r; ++q) row_ptr[q] = i;
    if (i == nnz - 1)
        for (int q = r + 1; q <= batch; ++q) row_ptr[q] = nnz;
}

__global__ __launch_bounds__(256) void spmm_wave_f32_kernel(
    const int* __restrict__ row_ptr,
    const int* __restrict__ cols,
    const float* __restrict__ vals,
    const float* __restrict__ weights,
    const float* __restrict__ bias,
    float* __restrict__ out,
    int batch)
{
    const int wave = threadIdx.x >> 6;
    const int lane = threadIdx.x & 63;
    const int row  = blockIdx.x * 4 + wave;
    if (row >= batch) return;

    const int lo = row_ptr[row];
    const int hi = row_ptr[row + 1];
    float4 acc0 = make_float4(0.f, 0.f, 0.f, 0.f);
    float4 acc1 = make_float4(0.f, 0.f, 0.f, 0.f);
    const bool tail = (lane < 75 - 64);

    for (int base = lo; base < hi; base += 64) {
        const int rem = hi - base;
        const int cnt = rem < 64 ? rem : 64;
        int   c = 0;
        float v = 0.0f;
        if (lane < cnt) { c = cols[base + lane]; v = vals[base + lane]; }
        const int rounds = (cnt + 7) & ~7;
        for (int k = 0; k < rounds; k += 8) {
#pragma unroll
            for (int u = 0; u < 8; ++u) {
                const int   cc = __shfl(c, k + u);
                const float vv = __shfl(v, k + u);
                const float4* wrow = (const float4*)(weights + (size_t)cc * OUT_DIM);
                float4 w0 = wrow[lane];
                acc0.x += vv * w0.x; acc0.y += vv * w0.y;
                acc0.z += vv * w0.z; acc0.w += vv * w0.w;
                if (tail) {
                    float4 w1 = wrow[64 + lane];
                    acc1.x += vv * w1.x; acc1.y += vv * w1.y;
                    acc1.z += vv * w1.z; acc1.w += vv * w1.w;
                }
            }
        }
    }

    const float4* b4 = (const float4*)bias;
    float4* orow = (float4*)(out + (size_t)row * OUT_DIM);
    float4 b0 = b4[lane];
    float4 r0;
    r0.x = fmaxf(acc0.x + b0.x, 0.f);
    r0.y = fmaxf(acc0.y + b0.y, 0.f);
    r0.z = fmaxf(acc0.z + b0.z, 0.f);
    r0.w = fmaxf(acc0.w + b0.w, 0.f);
    orow[lane] = r0;
    if (tail) {
        float4 b1 = b4[64 + lane];
        float4 r1;
        r1.x = fmaxf(acc1.x + b1.x, 0.f);
        r1.y = fmaxf(acc1.y + b1.y, 0.f);
        r1.z = fmaxf(acc1.z + b1.z, 0.f);
        r1.w = fmaxf(acc1.w + b1.w, 0.f);
        orow[64 + lane] = r1;
    }
}

// ---------------------------------------------------------------------------
extern "C" void kernel_launch(void* const* d_in, const int* in_sizes, int n_in,
                              void* d_out, int out_size, void* d_ws, size_t ws_size,
                              hipStream_t stream) {
    const int*   sp_rows = (const int*)d_in[0];
    const int*   sp_cols = (const int*)d_in[1];
    const float* sp_vals = (const float*)d_in[2];
    const float* weights = (const float*)d_in[3];
    const float* bias    = (const float*)d_in[4];
    float* out = (float*)d_out;

    const int nnz    = in_sizes[0];
    const int w_elts = in_sizes[3];
    const int in_dim = w_elts / OUT_DIM;           // 30000
    const int batch  = out_size / OUT_DIM;         // 16384

    size_t rp_bytes = (size_t)(batch + 1) * sizeof(int);
    size_t wf_off   = (rp_bytes + 255) & ~(size_t)255;
    size_t need4    = wf_off + (size_t)in_dim * 4 * 160 + 256;  // 19.2 MB

    int* row_ptr = (int*)d_ws;

    if (ws_size >= need4) {
        unsigned char* wf = (unsigned char*)d_ws + wf_off;
        const int scat_blocks = (nnz + 255) / 256;
        const int bps = (in_dim * 20 + 255) / 256;          // blocks per slice
        setup4x_kernel<<<scat_blocks + 4 * bps, 256, 0, stream>>>(
            sp_rows, row_ptr, weights, wf, nnz, batch, in_dim, scat_blocks);
        const int rowblocks16 = (batch + 15) / 16;          // 4 rows/wave x 4 waves
        spmm4r<<<rowblocks16 * 4, 256, 0, stream>>>(
            row_ptr, sp_cols, sp_vals, wf, bias, out, batch, in_dim);
    } else {
        row_ptr_scatter<<<(nnz + 255) / 256, 256, 0, stream>>>(
            sp_rows, row_ptr, nnz, batch);
        spmm_wave_f32_kernel<<<(batch + 3) / 4, 256, 0, stream>>>(
            row_ptr, sp_cols, sp_vals, weights, bias, out, batch);
    }
}